// Round 1
// baseline (541.367 us; speedup 1.0000x reference)
//
#include <hip/hip_runtime.h>
#include <math.h>

#define NB    4      // batches per block-iteration
#define TDP   132    // padded row stride for 128-wide rows (132%4==0, breaks bank stride)
#define SROW  16
#define BTOT  16384
#define GRID  256
#define NITER 16     // BTOT / (GRID*NB)

__device__ __forceinline__ float sigf(float x) { return 1.0f / (1.0f + expf(-x)); }

// M[k][j] such that q_flat = m_flat @ M reproduces the complex linear (x @ w.T form)
__device__ __forceinline__ float Mmat(const float* __restrict__ wr,
                                      const float* __restrict__ wi, int k, int j) {
    if (j < 64) return (k < 64) ? wr[j * 64 + k] : -wi[j * 64 + (k - 64)];
    return (k < 64) ? wi[(j - 64) * 64 + k] : wr[(j - 64) * 64 + (k - 64)];
}

// Build G = scale * Mq @ Mk^T (128x128) and Mv (128x128); zero the active-slot counter.
__global__ void prep_kernel(const float* __restrict__ wqr, const float* __restrict__ wqi,
                            const float* __restrict__ wkr, const float* __restrict__ wki,
                            const float* __restrict__ wvr, const float* __restrict__ wvi,
                            float* __restrict__ G, float* __restrict__ Mv,
                            int* __restrict__ cnt) {
    const int a = blockIdx.x;    // 0..127 (row of G: index into m[s])
    const int bb = threadIdx.x;  // 0..127 (col of G: index into m[t])
    if (a == 0 && bb == 0) *cnt = 0;
    float acc = 0.f;
    for (int j = 0; j < 128; ++j)
        acc += Mmat(wqr, wqi, a, j) * Mmat(wkr, wki, bb, j);
    G[a * 128 + bb] = 0.125f * acc;  // scale = D^-0.5 folded in
    Mv[a * 128 + bb] = Mmat(wvr, wvi, a, bb);
}

__global__ __launch_bounds__(256, 1) void crsn_main(
    const float* __restrict__ z_real, const float* __restrict__ z_imag,
    const float* __restrict__ mem, const float* __restrict__ ptr,
    const float* __restrict__ ctrl, const float* __restrict__ Gg,
    const float* __restrict__ Mvg,
    float* __restrict__ o_zr, float* __restrict__ o_zi,
    float* __restrict__ o_mem, float* __restrict__ o_np,
    int* __restrict__ g_cnt) {
    __shared__ float Gs[128 * TDP];           // 67584 B
    __shared__ float ms[NB * SROW * TDP];     // 33792 B  (blended mem tiles)
    __shared__ float t1s[NB * SROW * TDP];    // 33792 B  (t1 = m @ G)
    __shared__ float sc[NB][SROW * 17];       // scores/attn, padded rows
    __shared__ float npl[NB][16];
    __shared__ float wl[NB][16];
    __shared__ float cl[NB][128];
    __shared__ float pushl[NB], popl[NB], stayl[NB];
    __shared__ int cnt_lds;

    const int tid = threadIdx.x;
    const int w = tid >> 6;     // wave 0..3
    const int lane = tid & 63;

    if (tid == 0) cnt_lds = 0;
    // Stage G into LDS once (padded rows)
#pragma unroll
    for (int r = 0; r < 16; ++r) {
        int f = tid + 256 * r;   // float4 index 0..4095
        int a = f >> 5;
        int jq = f & 31;
        *(float4*)&Gs[a * TDP + (jq << 2)] = *(const float4*)(Gg + (f << 2));
    }
    __syncthreads();

    for (int it = 0; it < NITER; ++it) {
        const int base = blockIdx.x * (NB * NITER) + it * NB;

        if (tid < NB) {
            int b = base + tid;
            float g0 = sigf(ctrl[b * 3 + 0]);
            float g1 = sigf(ctrl[b * 3 + 1]);
            float g2 = sigf(ctrl[b * 3 + 2]);
            float tot = g0 + g1 + g2 + 1e-6f;
            pushl[tid] = g0 / tot; popl[tid] = g1 / tot; stayl[tid] = g2 / tot;
        }
        __syncthreads();

        // ---- Phase 1: blend -> mem_new (global) + m tiles (LDS) ----
#pragma unroll
        for (int r = 0; r < 8; ++r) {
            int f = tid + 256 * r;   // float4 index over 4 batches * 16 rows * 32 f4
            int nb = f >> 9;
            int rem = f & 511;
            int su = rem >> 5;
            int kq = rem & 31;
            int k = kq << 2;
            int b = base + nb;
            float p = pushl[nb];
            const float4 m4 = *(const float4*)(mem + ((((b << 4) + su) << 7) + k));
            float4 z4 = (k < 64) ? *(const float4*)(z_real + (b << 6) + k)
                                 : *(const float4*)(z_imag + (b << 6) + k - 64);
            float q = 1.0f - p;
            float4 mn;
            mn.x = m4.x * q + p * z4.x;
            mn.y = m4.y * q + p * z4.y;
            mn.z = m4.z * q + p * z4.z;
            mn.w = m4.w * q + p * z4.w;
            *(float4*)(o_mem + ((((b << 4) + su) << 7) + k)) = mn;
            *(float4*)&ms[nb * (SROW * TDP) + su * TDP + k] = mn;
        }
        __syncthreads();

        // ---- Phase 2: t1 = m @ G for all 4 batches; wave w owns j-slice [w*32, w*32+32) ----
        {
            const int su = lane >> 2;
            const int jb = (w << 5) + ((lane & 3) << 2);  // lane's base col
            float acc[NB][8];
#pragma unroll
            for (int nb = 0; nb < NB; ++nb)
#pragma unroll
                for (int x = 0; x < 8; ++x) acc[nb][x] = 0.f;

            for (int k0 = 0; k0 < 128; k0 += 4) {
                float mk[NB][4];
#pragma unroll
                for (int nb = 0; nb < NB; ++nb) {
                    float4 t = *(const float4*)&ms[nb * (SROW * TDP) + su * TDP + k0];
                    mk[nb][0] = t.x; mk[nb][1] = t.y; mk[nb][2] = t.z; mk[nb][3] = t.w;
                }
#pragma unroll
                for (int kk = 0; kk < 4; ++kk) {
#pragma unroll
                    for (int c = 0; c < 2; ++c) {
                        float4 g4 = *(const float4*)&Gs[(k0 + kk) * TDP + jb + (c << 4)];
#pragma unroll
                        for (int nb = 0; nb < NB; ++nb) {
                            acc[nb][c * 4 + 0] += mk[nb][kk] * g4.x;
                            acc[nb][c * 4 + 1] += mk[nb][kk] * g4.y;
                            acc[nb][c * 4 + 2] += mk[nb][kk] * g4.z;
                            acc[nb][c * 4 + 3] += mk[nb][kk] * g4.w;
                        }
                    }
                }
            }
#pragma unroll
            for (int nb = 0; nb < NB; ++nb)
#pragma unroll
                for (int c = 0; c < 2; ++c)
                    *(float4*)&t1s[nb * (SROW * TDP) + su * TDP + jb + (c << 4)] =
                        make_float4(acc[nb][c * 4 + 0], acc[nb][c * 4 + 1],
                                    acc[nb][c * 4 + 2], acc[nb][c * 4 + 3]);
        }
        __syncthreads();

        // ---- Phase 3: attention for batch (base + w), wave-local ----
        {
            const int b2 = base + w;
            const int su2 = lane >> 2;
            const int tg = lane & 3;

            // scores[s][t] = sum_j t1[s][j]*m[t][j]; each lane does 32 j's, reduce over quad
            float sp[16];
#pragma unroll
            for (int t = 0; t < 16; ++t) sp[t] = 0.f;
#pragma unroll
            for (int cc = 0; cc < 8; ++cc) {
                int jo = (tg << 2) + (cc << 4);
                float4 a4 = *(const float4*)&t1s[w * (SROW * TDP) + su2 * TDP + jo];
#pragma unroll
                for (int t = 0; t < 16; ++t) {
                    float4 b4 = *(const float4*)&ms[w * (SROW * TDP) + t * TDP + jo];
                    sp[t] += a4.x * b4.x + a4.y * b4.y + a4.z * b4.z + a4.w * b4.w;
                }
            }
#pragma unroll
            for (int t = 0; t < 16; ++t) {
                float v = sp[t];
                v += __shfl_xor(v, 1);
                v += __shfl_xor(v, 2);
                sp[t] = v;
            }
            if (tg == 0) {
#pragma unroll
                for (int t = 0; t < 16; ++t) sc[w][su2 * 17 + t] = sp[t];
            }

            // new_ptr, softmax (16 lanes, one row each)
            float npv = 0.f;
            if (lane < 16) {
                int si = lane;
                float pv = ptr[(b2 << 4) + si];
                float up = ptr[(b2 << 4) + ((si + 15) & 15)];
                float dn = ptr[(b2 << 4) + ((si + 1) & 15)];
                npv = pushl[w] * up + popl[w] * dn + stayl[w] * pv;
                o_np[(b2 << 4) + si] = npv;
                npl[w][si] = npv;
                float mx = -3.4e38f;
#pragma unroll
                for (int t = 0; t < 16; ++t) mx = fmaxf(mx, sc[w][si * 17 + t]);
                float e[16]; float ssum = 0.f;
#pragma unroll
                for (int t = 0; t < 16; ++t) { e[t] = expf(sc[w][si * 17 + t] - mx); ssum += e[t]; }
                float inv = 1.0f / ssum;
#pragma unroll
                for (int t = 0; t < 16; ++t) sc[w][si * 17 + t] = e[t] * inv;
            }
            unsigned long long bal = __ballot(npv > 0.1f);
            if (lane == 0) atomicAdd(&cnt_lds, (int)__popcll(bal));

            // w[t] = sum_s new_ptr[s] * attn[s][t]
            if (lane < 16) {
                int t = lane;
                float wv = 0.f;
#pragma unroll
                for (int s2 = 0; s2 < 16; ++s2) wv += npl[w][s2] * sc[w][s2 * 17 + t];
                wl[w][t] = wv;
            }
            // c[k] = sum_t w[t] * m[t][k]
            {
                float c1 = 0.f, c2 = 0.f;
#pragma unroll
                for (int t = 0; t < 16; ++t) {
                    float wv = wl[w][t];
                    c1 += wv * ms[w * (SROW * TDP) + t * TDP + lane];
                    c2 += wv * ms[w * (SROW * TDP) + t * TDP + 64 + lane];
                }
                cl[w][lane] = c1; cl[w][64 + lane] = c2;
            }
            // read[j] = sum_k c[k] * Mv[k][j]; lane covers j = 2*lane, 2*lane+1
            {
                float r0 = 0.f, r1 = 0.f;
#pragma unroll 4
                for (int k = 0; k < 128; ++k) {
                    float cv = cl[w][k];
                    float2 m2 = *(const float2*)(Mvg + (k << 7) + (lane << 1));
                    r0 += cv * m2.x; r1 += cv * m2.y;
                }
                float2 o; o.x = r0; o.y = r1;
                if (lane < 32) *(float2*)(o_zr + (b2 << 6) + (lane << 1)) = o;
                else           *(float2*)(o_zi + (b2 << 6) + ((lane - 32) << 1)) = o;
            }
        }
        __syncthreads();
    }
    __syncthreads();
    if (tid == 0) atomicAdd(g_cnt, cnt_lds);
}

__global__ void fin_kernel(const int* __restrict__ cnt, float* __restrict__ o_act) {
    *o_act = (float)(*cnt) / 16384.0f;
}

extern "C" void kernel_launch(void* const* d_in, const int* in_sizes, int n_in,
                              void* d_out, int out_size, void* d_ws, size_t ws_size,
                              hipStream_t stream) {
    const float* z_real = (const float*)d_in[0];
    const float* z_imag = (const float*)d_in[1];
    const float* mem    = (const float*)d_in[2];
    const float* ptr    = (const float*)d_in[3];
    const float* ctrl   = (const float*)d_in[4];
    const float* wqr = (const float*)d_in[5];
    const float* wqi = (const float*)d_in[6];
    const float* wkr = (const float*)d_in[7];
    const float* wki = (const float*)d_in[8];
    const float* wvr = (const float*)d_in[9];
    const float* wvi = (const float*)d_in[10];

    float* out = (float*)d_out;
    float* o_zr  = out;                       // B*64
    float* o_zi  = out + 16384 * 64;          // B*64
    float* o_mem = out + 2 * 16384 * 64;      // B*16*128
    float* o_np  = o_mem + 16384 * 16 * 128;  // B*16
    float* o_act = o_np + 16384 * 16;         // 1

    int* cnt = (int*)d_ws;
    float* G  = (float*)((char*)d_ws + 256);
    float* Mv = G + 128 * 128;

    hipLaunchKernelGGL(prep_kernel, dim3(128), dim3(128), 0, stream,
                       wqr, wqi, wkr, wki, wvr, wvi, G, Mv, cnt);
    hipLaunchKernelGGL(crsn_main, dim3(GRID), dim3(256), 0, stream,
                       z_real, z_imag, mem, ptr, ctrl, G, Mv,
                       o_zr, o_zi, o_mem, o_np, cnt);
    hipLaunchKernelGGL(fin_kernel, dim3(1), dim3(1), 0, stream, cnt, o_act);
}

// Round 2
// 375.787 us; speedup vs baseline: 1.4406x; 1.4406x over previous
//
#include <hip/hip_runtime.h>
#include <math.h>

#define GRID  256
#define BLK   512
#define NB    8
#define NITER 8      // 16384 / (GRID*NB)

typedef __attribute__((ext_vector_type(8))) short short8;
typedef __attribute__((ext_vector_type(4))) float f32x4;

__device__ __forceinline__ float sigf(float x) { return 1.0f / (1.0f + expf(-x)); }

__device__ __forceinline__ unsigned short f2bf(float x) {
    unsigned u = __float_as_uint(x);
    return (unsigned short)((u + 0x7fffu + ((u >> 16) & 1u)) >> 16);
}
__device__ __forceinline__ float bf2f(unsigned short h) {
    return __uint_as_float(((unsigned)h) << 16);
}

__device__ __forceinline__ void split8(const float4 p0, const float4 p1,
                                       short8& hi, short8& lo) {
    float xs[8] = {p0.x, p0.y, p0.z, p0.w, p1.x, p1.y, p1.z, p1.w};
#pragma unroll
    for (int i = 0; i < 8; ++i) {
        unsigned short h = f2bf(xs[i]);
        hi[i] = (short)h;
        lo[i] = (short)f2bf(xs[i] - bf2f(h));
    }
}

// M[k][j] such that q_flat = m_flat @ M reproduces the complex linear
__device__ __forceinline__ float Mmat(const float* __restrict__ wr,
                                      const float* __restrict__ wi, int k, int j) {
    if (j < 64) return (k < 64) ? wr[j * 64 + k] : -wi[j * 64 + (k - 64)];
    return (k < 64) ? wi[(j - 64) * 64 + k] : wr[(j - 64) * 64 + (k - 64)];
}

// Build G = scale * Mq @ Mk^T (128x128) and Mv (128x128); zero counter.
__global__ void prep_kernel(const float* __restrict__ wqr, const float* __restrict__ wqi,
                            const float* __restrict__ wkr, const float* __restrict__ wki,
                            const float* __restrict__ wvr, const float* __restrict__ wvi,
                            float* __restrict__ G, float* __restrict__ Mv,
                            int* __restrict__ cnt) {
    const int a = blockIdx.x;    // k-row
    const int bb = threadIdx.x;  // j-col
    if (a == 0 && bb == 0) *cnt = 0;
    float acc = 0.f;
    for (int j = 0; j < 128; ++j)
        acc += Mmat(wqr, wqi, a, j) * Mmat(wkr, wki, bb, j);
    G[a * 128 + bb] = 0.125f * acc;  // scale = D^-0.5 folded in
    Mv[a * 128 + bb] = Mmat(wvr, wvi, a, bb);
}

// Pre-fragment G and Mv into MFMA B-operand layout, bf16 hi/lo planes.
// Layout: [(jt*4 + t)*2 + plane][lane][i]  (512 bf16 per frag), value =
// plane(X[k = t*32 + (lane>>4)*8 + i][j = jt*16 + (lane&15)])
__global__ void prep_frag(const float* __restrict__ G, const float* __restrict__ Mv,
                          unsigned short* __restrict__ Gf, unsigned short* __restrict__ Mvf) {
    const int bid = blockIdx.x;     // 64 = mat(2) * jt(8) * t(4)
    const int lane = threadIdx.x;   // 64
    const int mat = bid >> 5, jt = (bid >> 2) & 7, t = bid & 3;
    const float* X = mat ? Mv : G;
    unsigned short* O = mat ? Mvf : Gf;
    const int quad = lane >> 4, col = lane & 15;
    const int obase = ((jt * 4 + t) * 2) * 512 + lane * 8;
#pragma unroll
    for (int i = 0; i < 8; ++i) {
        int k = t * 32 + quad * 8 + i;
        int j = jt * 16 + col;
        float x = X[k * 128 + j];
        unsigned short h = f2bf(x);
        O[obase + i] = h;
        O[obase + 512 + i] = f2bf(x - bf2f(h));
    }
}

__global__ __launch_bounds__(BLK, 2) void crsn_main(
    const float* __restrict__ z_real, const float* __restrict__ z_imag,
    const float* __restrict__ mem, const float* __restrict__ ptr,
    const float* __restrict__ ctrl,
    const unsigned short* __restrict__ Gf, const unsigned short* __restrict__ Mvf,
    float* __restrict__ o_zr, float* __restrict__ o_zi,
    float* __restrict__ o_mem, float* __restrict__ o_np,
    int* __restrict__ g_cnt) {
    // buf: phase1 = raw mem staging (16384 f); phase2/3 = t1 rows [nb][s][132]
    __shared__ __align__(16) float buf[16896];            // 67584 B
    __shared__ __align__(16) unsigned short mfrag[33280]; // 64 frags * 520 (+8 pad) = 66560 B
    __shared__ float npl[NB][16];
    __shared__ float wl[NB][16];
    __shared__ float pushl[NB], popl[NB], stayl[NB];
    __shared__ int cnt_lds;

    const int tid = threadIdx.x;
    const int w = tid >> 6;       // wave 0..7: owns j-tile jt = w (16 cols)
    const int lane = tid & 63;
    const int quad = lane >> 4;
    const int col = lane & 15;

    if (tid == 0) cnt_lds = 0;

    f32x4 acc1[NB], acc2[NB];

    for (int it = 0; it < NITER; ++it) {
        const int base = blockIdx.x * (NB * NITER) + it * NB;

        if (tid < NB) {
            int b = base + tid;
            float g0 = sigf(ctrl[b * 3 + 0]);
            float g1 = sigf(ctrl[b * 3 + 1]);
            float g2 = sigf(ctrl[b * 3 + 2]);
            float tot = g0 + g1 + g2 + 1e-6f;
            pushl[tid] = g0 / tot; popl[tid] = g1 / tot; stayl[tid] = g2 / tot;
        }

        // ---- ph1a: async-stage 64 KB mem tile into buf (wave w copies 8 KB) ----
        {
            const float* gsrc = mem + (size_t)base * 2048 + w * 2048;
#pragma unroll
            for (int c = 0; c < 8; ++c) {
                __builtin_amdgcn_global_load_lds(
                    (const __attribute__((address_space(1))) unsigned int*)(gsrc + c * 256 + lane * 4),
                    (__attribute__((address_space(3))) unsigned int*)(&buf[w * 2048 + c * 256]),
                    16, 0, 0);
            }
        }
        __syncthreads();  // B1: staging + gates visible

        // ---- ph1b: blend -> o_mem (global) + mfrag hi/lo (LDS, A-frag layout) ----
#pragma unroll
        for (int r = 0; r < 8; ++r) {
            int f = tid + BLK * r;
            int nb = f >> 9, rem = f & 511, su = rem >> 5, kq = rem & 31, k = kq << 2;
            int b = base + nb;
            float p = pushl[nb], q = 1.0f - p;
            float4 m4 = *(const float4*)&buf[nb * 2048 + su * 128 + k];
            float4 z4 = (k < 64) ? *(const float4*)(z_real + (b << 6) + k)
                                 : *(const float4*)(z_imag + (b << 6) + k - 64);
            float4 mn;
            mn.x = m4.x * q + p * z4.x;
            mn.y = m4.y * q + p * z4.y;
            mn.z = m4.z * q + p * z4.z;
            mn.w = m4.w * q + p * z4.w;
            *(float4*)(o_mem + (size_t)b * 2048 + su * 128 + k) = mn;
            // frag store: element (su, k) -> frag[(nb*4+t)*2+pl], lane' = quad2*16+su, i = k&7
            int t = k >> 5, q2 = (k >> 3) & 3, i0 = k & 7;
            int bidx = ((nb * 4 + t) * 2) * 520 + (q2 * 16 + su) * 8 + i0;
            ushort4 hv;
            hv.x = f2bf(mn.x); hv.y = f2bf(mn.y); hv.z = f2bf(mn.z); hv.w = f2bf(mn.w);
            ushort4 lv;
            lv.x = f2bf(mn.x - bf2f(hv.x));
            lv.y = f2bf(mn.y - bf2f(hv.y));
            lv.z = f2bf(mn.z - bf2f(hv.z));
            lv.w = f2bf(mn.w - bf2f(hv.w));
            *(ushort4*)&mfrag[bidx] = hv;
            *(ushort4*)&mfrag[bidx + 520] = lv;
        }
        __syncthreads();  // B2: mfrag ready, staging consumed (buf free for t1)

        // ---- ph2: t1 = m@G, t2 = m@Mv via MFMA (hi/lo split, 3 products) ----
        {
#pragma unroll
            for (int nb = 0; nb < NB; ++nb) {
                acc1[nb] = (f32x4){0.f, 0.f, 0.f, 0.f};
                acc2[nb] = (f32x4){0.f, 0.f, 0.f, 0.f};
            }
#pragma unroll
            for (int t = 0; t < 4; ++t) {
                const int fb = ((w * 4 + t) * 2) * 512 + lane * 8;
                short8 Gh = *(const short8*)(Gf + fb);
                short8 Gl = *(const short8*)(Gf + fb + 512);
                short8 Mh = *(const short8*)(Mvf + fb);
                short8 Ml = *(const short8*)(Mvf + fb + 512);
#pragma unroll
                for (int nb = 0; nb < NB; ++nb) {
                    const unsigned short* mp = &mfrag[((nb * 4 + t) * 2) * 520 + lane * 8];
                    short8 ah = *(const short8*)mp;
                    short8 al = *(const short8*)(mp + 520);
                    acc1[nb] = __builtin_amdgcn_mfma_f32_16x16x32_bf16(ah, Gh, acc1[nb], 0, 0, 0);
                    acc1[nb] = __builtin_amdgcn_mfma_f32_16x16x32_bf16(ah, Gl, acc1[nb], 0, 0, 0);
                    acc1[nb] = __builtin_amdgcn_mfma_f32_16x16x32_bf16(al, Gh, acc1[nb], 0, 0, 0);
                    acc2[nb] = __builtin_amdgcn_mfma_f32_16x16x32_bf16(ah, Mh, acc2[nb], 0, 0, 0);
                    acc2[nb] = __builtin_amdgcn_mfma_f32_16x16x32_bf16(ah, Ml, acc2[nb], 0, 0, 0);
                    acc2[nb] = __builtin_amdgcn_mfma_f32_16x16x32_bf16(al, Mh, acc2[nb], 0, 0, 0);
                }
            }
            // write t1 C-layout (row = quad*4+reg, col = w*16 + lane&15) to buf
#pragma unroll
            for (int nb = 0; nb < NB; ++nb) {
#pragma unroll
                for (int reg = 0; reg < 4; ++reg)
                    buf[nb * 2112 + (quad * 4 + reg) * 132 + w * 16 + col] = acc1[nb][reg];
            }
        }
        __syncthreads();  // B3: t1 ready

        // ---- ph3a: wave w handles batch base+w: new_ptr, scores MFMA, softmax, w[t] ----
        {
            const int b2 = base + w;
            float npv = 0.f;
            if (lane < 16) {
                float pv = ptr[(b2 << 4) + lane];
                float up = ptr[(b2 << 4) + ((lane + 15) & 15)];
                float dn = ptr[(b2 << 4) + ((lane + 1) & 15)];
                npv = pushl[w] * up + popl[w] * dn + stayl[w] * pv;
                o_np[(b2 << 4) + lane] = npv;
                npl[w][lane] = npv;
            }
            unsigned long long bal = __ballot(npv > 0.1f);
            if (lane == 0) atomicAdd(&cnt_lds, (int)__popcll(bal));

            f32x4 sc = (f32x4){0.f, 0.f, 0.f, 0.f};
#pragma unroll
            for (int t = 0; t < 4; ++t) {
                // A-frag of t1: lane holds t1[s=col][k=t*32+quad*8+i]
                const float* tp = &buf[w * 2112 + col * 132 + t * 32 + quad * 8];
                float4 p0 = *(const float4*)tp;
                float4 p1 = *(const float4*)(tp + 4);
                short8 ah, al;
                split8(p0, p1, ah, al);
                // B-frag of m^T == A-frag of m (already staged)
                const unsigned short* mp = &mfrag[((w * 4 + t) * 2) * 520 + lane * 8];
                short8 bh = *(const short8*)mp;
                short8 bl = *(const short8*)(mp + 520);
                sc = __builtin_amdgcn_mfma_f32_16x16x32_bf16(ah, bh, sc, 0, 0, 0);
                sc = __builtin_amdgcn_mfma_f32_16x16x32_bf16(ah, bl, sc, 0, 0, 0);
                sc = __builtin_amdgcn_mfma_f32_16x16x32_bf16(al, bh, sc, 0, 0, 0);
            }
            // softmax over t (= cols = lanes within 16-group); rows = quad*4+reg
            float at[4];
#pragma unroll
            for (int reg = 0; reg < 4; ++reg) {
                float v = sc[reg];
                float mx = v;
                mx = fmaxf(mx, __shfl_xor(mx, 1));
                mx = fmaxf(mx, __shfl_xor(mx, 2));
                mx = fmaxf(mx, __shfl_xor(mx, 4));
                mx = fmaxf(mx, __shfl_xor(mx, 8));
                float e = expf(v - mx);
                float s2 = e;
                s2 += __shfl_xor(s2, 1);
                s2 += __shfl_xor(s2, 2);
                s2 += __shfl_xor(s2, 4);
                s2 += __shfl_xor(s2, 8);
                at[reg] = e / s2;
            }
            float wv = npl[w][quad * 4 + 0] * at[0] + npl[w][quad * 4 + 1] * at[1]
                     + npl[w][quad * 4 + 2] * at[2] + npl[w][quad * 4 + 3] * at[3];
            wv += __shfl_xor(wv, 16);
            wv += __shfl_xor(wv, 32);
            if (lane < 16) wl[w][lane] = wv;
        }
        __syncthreads();  // B4: wl ready; buf/mfrag free for next iter

        // ---- ph3b: read[j] = sum_slot w[slot]*t2[slot][j] from live C-frags ----
#pragma unroll
        for (int nb = 0; nb < NB; ++nb) {
            float pr = wl[nb][quad * 4 + 0] * acc2[nb][0]
                     + wl[nb][quad * 4 + 1] * acc2[nb][1]
                     + wl[nb][quad * 4 + 2] * acc2[nb][2]
                     + wl[nb][quad * 4 + 3] * acc2[nb][3];
            pr += __shfl_xor(pr, 16);
            pr += __shfl_xor(pr, 32);
            if (lane < 16) {
                int j = w * 16 + lane;
                int b2 = base + nb;
                if (j < 64) o_zr[(b2 << 6) + j] = pr;
                else        o_zi[(b2 << 6) + j - 64] = pr;
            }
        }
    }
    __syncthreads();
    if (tid == 0) atomicAdd(g_cnt, cnt_lds);
}

__global__ void fin_kernel(const int* __restrict__ cnt, float* __restrict__ o_act) {
    *o_act = (float)(*cnt) / 16384.0f;
}

extern "C" void kernel_launch(void* const* d_in, const int* in_sizes, int n_in,
                              void* d_out, int out_size, void* d_ws, size_t ws_size,
                              hipStream_t stream) {
    const float* z_real = (const float*)d_in[0];
    const float* z_imag = (const float*)d_in[1];
    const float* mem    = (const float*)d_in[2];
    const float* ptr    = (const float*)d_in[3];
    const float* ctrl   = (const float*)d_in[4];
    const float* wqr = (const float*)d_in[5];
    const float* wqi = (const float*)d_in[6];
    const float* wkr = (const float*)d_in[7];
    const float* wki = (const float*)d_in[8];
    const float* wvr = (const float*)d_in[9];
    const float* wvi = (const float*)d_in[10];

    float* out = (float*)d_out;
    float* o_zr  = out;
    float* o_zi  = out + 16384 * 64;
    float* o_mem = out + 2 * 16384 * 64;
    float* o_np  = o_mem + 16384 * 16 * 128;
    float* o_act = o_np + 16384 * 16;

    int*   cnt = (int*)d_ws;
    float* G   = (float*)((char*)d_ws + 256);
    float* Mv  = G + 128 * 128;
    unsigned short* Gfr  = (unsigned short*)(Mv + 128 * 128);
    unsigned short* Mvfr = Gfr + 32768;

    hipLaunchKernelGGL(prep_kernel, dim3(128), dim3(128), 0, stream,
                       wqr, wqi, wkr, wki, wvr, wvi, G, Mv, cnt);
    hipLaunchKernelGGL(prep_frag, dim3(64), dim3(64), 0, stream, G, Mv, Gfr, Mvfr);
    hipLaunchKernelGGL(crsn_main, dim3(GRID), dim3(BLK), 0, stream,
                       z_real, z_imag, mem, ptr, ctrl, Gfr, Mvfr,
                       o_zr, o_zi, o_mem, o_np, cnt);
    hipLaunchKernelGGL(fin_kernel, dim3(1), dim3(1), 0, stream, cnt, o_act);
}

// Round 3
// 373.120 us; speedup vs baseline: 1.4509x; 1.0071x over previous
//
#include <hip/hip_runtime.h>
#include <math.h>

#define GRID  512
#define BLK   512
#define NB    4
#define NITER 8      // 16384 / (GRID*NB)

typedef __attribute__((ext_vector_type(8))) short short8;
typedef __attribute__((ext_vector_type(4))) float f32x4;

__device__ __forceinline__ float sigf(float x) { return 1.0f / (1.0f + expf(-x)); }

__device__ __forceinline__ unsigned short f2bf(float x) {
    unsigned u = __float_as_uint(x);
    return (unsigned short)((u + 0x7fffu + ((u >> 16) & 1u)) >> 16);
}
__device__ __forceinline__ float bf2f(unsigned short h) {
    return __uint_as_float(((unsigned)h) << 16);
}
__device__ __forceinline__ unsigned short f2bf_trunc(float x) {
    return (unsigned short)(__float_as_uint(x) >> 16);
}

__device__ __forceinline__ void split8(const float4 p0, const float4 p1,
                                       short8& hi, short8& lo) {
    float xs[8] = {p0.x, p0.y, p0.z, p0.w, p1.x, p1.y, p1.z, p1.w};
#pragma unroll
    for (int i = 0; i < 8; ++i) {
        unsigned short h = f2bf(xs[i]);
        hi[i] = (short)h;
        lo[i] = (short)f2bf_trunc(xs[i] - bf2f(h));
    }
}

// M[k][j] such that q_flat = m_flat @ M reproduces the complex linear
__device__ __forceinline__ float Mmat(const float* __restrict__ wr,
                                      const float* __restrict__ wi, int k, int j) {
    if (j < 64) return (k < 64) ? wr[j * 64 + k] : -wi[j * 64 + (k - 64)];
    return (k < 64) ? wi[(j - 64) * 64 + k] : wr[(j - 64) * 64 + (k - 64)];
}

__global__ void prep_kernel(const float* __restrict__ wqr, const float* __restrict__ wqi,
                            const float* __restrict__ wkr, const float* __restrict__ wki,
                            const float* __restrict__ wvr, const float* __restrict__ wvi,
                            float* __restrict__ G, float* __restrict__ Mv,
                            int* __restrict__ cnt) {
    const int a = blockIdx.x;
    const int bb = threadIdx.x;
    if (a == 0 && bb == 0) *cnt = 0;
    float acc = 0.f;
    for (int j = 0; j < 128; ++j)
        acc += Mmat(wqr, wqi, a, j) * Mmat(wkr, wki, bb, j);
    G[a * 128 + bb] = 0.125f * acc;
    Mv[a * 128 + bb] = Mmat(wvr, wvi, a, bb);
}

// Pre-fragment G and Mv into MFMA B-operand layout, bf16 hi/lo planes.
// [(jt*4 + t)*2 + plane][lane][i]; value = plane(X[k=t*32+(lane>>4)*8+i][j=jt*16+(lane&15)])
__global__ void prep_frag(const float* __restrict__ G, const float* __restrict__ Mv,
                          unsigned short* __restrict__ Gf, unsigned short* __restrict__ Mvf) {
    const int bid = blockIdx.x;     // 64 = mat(2) * jt(8) * t(4)
    const int lane = threadIdx.x;   // 64
    const int mat = bid >> 5, jt = (bid >> 2) & 7, t = bid & 3;
    const float* X = mat ? Mv : G;
    unsigned short* O = mat ? Mvf : Gf;
    const int quad = lane >> 4, col = lane & 15;
    const int obase = ((jt * 4 + t) * 2) * 512 + lane * 8;
#pragma unroll
    for (int i = 0; i < 8; ++i) {
        int k = t * 32 + quad * 8 + i;
        int j = jt * 16 + col;
        float x = X[k * 128 + j];
        unsigned short h = f2bf(x);
        O[obase + i] = h;
        O[obase + 512 + i] = f2bf_trunc(x - bf2f(h));
    }
}

__global__ __launch_bounds__(BLK, 4) void crsn_main(
    const float* __restrict__ z_real, const float* __restrict__ z_imag,
    const float* __restrict__ mem, const float* __restrict__ ptr,
    const float* __restrict__ ctrl,
    const unsigned short* __restrict__ Gf, const unsigned short* __restrict__ Mvf,
    float* __restrict__ o_zr, float* __restrict__ o_zi,
    float* __restrict__ o_mem, float* __restrict__ o_np,
    int* __restrict__ g_cnt) {
    // buf: per-batch 2112-float region; phase1 = raw staging (first 2048), ph2/3 = t1 [16][132]
    __shared__ __align__(16) float buf[NB * 2112];              // 33792 B
    __shared__ __align__(16) unsigned short mfrag[NB * 8 * 520]; // 33280 B
    __shared__ float wl[NB][16];
    __shared__ int cnt_lds;

    const int tid = threadIdx.x;
    const int w = tid >> 6;       // wave 0..7: owns j-tile jt = w
    const int lane = tid & 63;
    const int quad = lane >> 4;
    const int col = lane & 15;
    const int snb = w >> 1;       // batch this wave stages/blends
    const int half = w & 1;       // which half of the batch row-block

    if (tid == 0) cnt_lds = 0;

    f32x4 acc1[NB], acc2[NB];

    for (int it = 0; it < NITER; ++it) {
        const int base = blockIdx.x * (NB * NITER) + it * NB;
        const int bs = base + snb;

        // ---- ph1a: wave-local async stage of own quarter (1024 floats) ----
        {
            const float* gsrc = mem + (size_t)bs * 2048 + half * 1024;
#pragma unroll
            for (int c = 0; c < 4; ++c) {
                __builtin_amdgcn_global_load_lds(
                    (const __attribute__((address_space(1))) unsigned int*)(gsrc + c * 256 + lane * 4),
                    (__attribute__((address_space(3))) unsigned int*)(&buf[snb * 2112 + half * 1024 + c * 256]),
                    16, 0, 0);
            }
        }
        // gates for staged batch, in registers (every lane computes)
        float g0 = sigf(ctrl[bs * 3 + 0]);
        float g1 = sigf(ctrl[bs * 3 + 1]);
        float g2 = sigf(ctrl[bs * 3 + 2]);
        float push = g0 / (g0 + g1 + g2 + 1e-6f);
        float qq = 1.0f - push;

        __builtin_amdgcn_s_waitcnt(0x0f70);  // vmcnt(0), wave-local: own staging done

        // ---- ph1b: blend own quarter -> o_mem + mfrag hi/lo (A-frag layout) ----
#pragma unroll
        for (int c = 0; c < 4; ++c) {
            int fi = half * 256 + c * 64 + lane;   // float4 index within batch
            int su = fi >> 5, k = (fi & 31) << 2;
            float4 m4 = *(const float4*)&buf[snb * 2112 + fi * 4];
            float4 z4 = (k < 64) ? *(const float4*)(z_real + (bs << 6) + k)
                                 : *(const float4*)(z_imag + (bs << 6) + k - 64);
            float4 mn;
            mn.x = m4.x * qq + push * z4.x;
            mn.y = m4.y * qq + push * z4.y;
            mn.z = m4.z * qq + push * z4.z;
            mn.w = m4.w * qq + push * z4.w;
            *(float4*)(o_mem + (size_t)bs * 2048 + fi * 4) = mn;
            int t = k >> 5, q2 = (k >> 3) & 3, i0 = k & 7;
            int bidx = ((snb * 4 + t) * 2) * 520 + (q2 * 16 + su) * 8 + i0;
            ushort4 hv, lv;
            hv.x = f2bf(mn.x); hv.y = f2bf(mn.y); hv.z = f2bf(mn.z); hv.w = f2bf(mn.w);
            lv.x = f2bf_trunc(mn.x - bf2f(hv.x));
            lv.y = f2bf_trunc(mn.y - bf2f(hv.y));
            lv.z = f2bf_trunc(mn.z - bf2f(hv.z));
            lv.w = f2bf_trunc(mn.w - bf2f(hv.w));
            *(ushort4*)&mfrag[bidx] = hv;
            *(ushort4*)&mfrag[bidx + 520] = lv;
        }
        __syncthreads();  // B2: all mfrags ready

        // ---- ph2: t1 = m@G, t2 = m@Mv via MFMA (hi/lo split); wave w = j-tile w ----
        {
#pragma unroll
            for (int nb = 0; nb < NB; ++nb) {
                acc1[nb] = (f32x4){0.f, 0.f, 0.f, 0.f};
                acc2[nb] = (f32x4){0.f, 0.f, 0.f, 0.f};
            }
#pragma unroll
            for (int t = 0; t < 4; ++t) {
                const unsigned short* fb = Gf + ((w * 4 + t) * 2) * 512 + lane * 8;
                const unsigned short* fb2 = Mvf + ((w * 4 + t) * 2) * 512 + lane * 8;
                short8 Gh = *(const short8*)fb;
                short8 Gl = *(const short8*)(fb + 512);
                short8 Mh = *(const short8*)fb2;
                short8 Ml = *(const short8*)(fb2 + 512);
#pragma unroll
                for (int nb = 0; nb < NB; ++nb) {
                    const unsigned short* mp = &mfrag[((nb * 4 + t) * 2) * 520 + lane * 8];
                    short8 ah = *(const short8*)mp;
                    short8 al = *(const short8*)(mp + 520);
                    acc1[nb] = __builtin_amdgcn_mfma_f32_16x16x32_bf16(ah, Gh, acc1[nb], 0, 0, 0);
                    acc1[nb] = __builtin_amdgcn_mfma_f32_16x16x32_bf16(ah, Gl, acc1[nb], 0, 0, 0);
                    acc1[nb] = __builtin_amdgcn_mfma_f32_16x16x32_bf16(al, Gh, acc1[nb], 0, 0, 0);
                    acc2[nb] = __builtin_amdgcn_mfma_f32_16x16x32_bf16(ah, Mh, acc2[nb], 0, 0, 0);
                    acc2[nb] = __builtin_amdgcn_mfma_f32_16x16x32_bf16(ah, Ml, acc2[nb], 0, 0, 0);
                    acc2[nb] = __builtin_amdgcn_mfma_f32_16x16x32_bf16(al, Mh, acc2[nb], 0, 0, 0);
                }
            }
            // t1 C-layout (row = quad*4+reg, col = w*16+col) -> buf
#pragma unroll
            for (int nb = 0; nb < NB; ++nb)
#pragma unroll
                for (int reg = 0; reg < 4; ++reg)
                    buf[nb * 2112 + (quad * 4 + reg) * 132 + w * 16 + col] = acc1[nb][reg];
        }
        __syncthreads();  // B3: t1 ready

        // ---- ph3a: waves 0..3: batch base+w attention ----
        if (w < NB) {
            const int b2 = base + w;
            // gates for this batch (recompute in registers)
            float h0 = sigf(ctrl[b2 * 3 + 0]);
            float h1 = sigf(ctrl[b2 * 3 + 1]);
            float h2 = sigf(ctrl[b2 * 3 + 2]);
            float ht = h0 + h1 + h2 + 1e-6f;
            float pushb = h0 / ht, popb = h1 / ht, stayb = h2 / ht;

            int s = lane & 15;
            float pv = ptr[(b2 << 4) + s];
            float up = ptr[(b2 << 4) + ((s + 15) & 15)];
            float dn = ptr[(b2 << 4) + ((s + 1) & 15)];
            float npv = pushb * up + popb * dn + stayb * pv;
            if (lane < 16) o_np[(b2 << 4) + lane] = npv;
            unsigned long long bal = __ballot(lane < 16 && npv > 0.1f);
            if (lane == 0) atomicAdd(&cnt_lds, (int)__popcll(bal));

            f32x4 sc = (f32x4){0.f, 0.f, 0.f, 0.f};
#pragma unroll
            for (int t = 0; t < 4; ++t) {
                const float* tp = &buf[w * 2112 + col * 132 + t * 32 + quad * 8];
                float4 p0 = *(const float4*)tp;
                float4 p1 = *(const float4*)(tp + 4);
                short8 ah, al;
                split8(p0, p1, ah, al);
                const unsigned short* mp = &mfrag[((w * 4 + t) * 2) * 520 + lane * 8];
                short8 bh = *(const short8*)mp;
                short8 bl = *(const short8*)(mp + 520);
                sc = __builtin_amdgcn_mfma_f32_16x16x32_bf16(ah, bh, sc, 0, 0, 0);
                sc = __builtin_amdgcn_mfma_f32_16x16x32_bf16(ah, bl, sc, 0, 0, 0);
                sc = __builtin_amdgcn_mfma_f32_16x16x32_bf16(al, bh, sc, 0, 0, 0);
            }
            float at[4];
#pragma unroll
            for (int reg = 0; reg < 4; ++reg) {
                float v = sc[reg];
                float mx = v;
                mx = fmaxf(mx, __shfl_xor(mx, 1));
                mx = fmaxf(mx, __shfl_xor(mx, 2));
                mx = fmaxf(mx, __shfl_xor(mx, 4));
                mx = fmaxf(mx, __shfl_xor(mx, 8));
                float e = expf(v - mx);
                float s2 = e;
                s2 += __shfl_xor(s2, 1);
                s2 += __shfl_xor(s2, 2);
                s2 += __shfl_xor(s2, 4);
                s2 += __shfl_xor(s2, 8);
                at[reg] = e / s2;
            }
            float wv = __shfl(npv, quad * 4 + 0) * at[0] + __shfl(npv, quad * 4 + 1) * at[1]
                     + __shfl(npv, quad * 4 + 2) * at[2] + __shfl(npv, quad * 4 + 3) * at[3];
            wv += __shfl_xor(wv, 16);
            wv += __shfl_xor(wv, 32);
            if (lane < 16) wl[w][lane] = wv;
        }
        __syncthreads();  // B4: wl ready; buf/mfrag safe to reuse

        // ---- ph3b: read[j] from live t2 C-frags; wave w covers j = w*16..w*16+15 ----
#pragma unroll
        for (int nb = 0; nb < NB; ++nb) {
            float pr = wl[nb][quad * 4 + 0] * acc2[nb][0]
                     + wl[nb][quad * 4 + 1] * acc2[nb][1]
                     + wl[nb][quad * 4 + 2] * acc2[nb][2]
                     + wl[nb][quad * 4 + 3] * acc2[nb][3];
            pr += __shfl_xor(pr, 16);
            pr += __shfl_xor(pr, 32);
            if (lane < 16) {
                int j = (w << 4) + lane;
                int b2 = base + nb;
                if (j < 64) o_zr[(b2 << 6) + j] = pr;
                else        o_zi[(b2 << 6) + j - 64] = pr;
            }
        }
    }
    __syncthreads();
    if (tid == 0) atomicAdd(g_cnt, cnt_lds);
}

__global__ void fin_kernel(const int* __restrict__ cnt, float* __restrict__ o_act) {
    *o_act = (float)(*cnt) / 16384.0f;
}

extern "C" void kernel_launch(void* const* d_in, const int* in_sizes, int n_in,
                              void* d_out, int out_size, void* d_ws, size_t ws_size,
                              hipStream_t stream) {
    const float* z_real = (const float*)d_in[0];
    const float* z_imag = (const float*)d_in[1];
    const float* mem    = (const float*)d_in[2];
    const float* ptr    = (const float*)d_in[3];
    const float* ctrl   = (const float*)d_in[4];
    const float* wqr = (const float*)d_in[5];
    const float* wqi = (const float*)d_in[6];
    const float* wkr = (const float*)d_in[7];
    const float* wki = (const float*)d_in[8];
    const float* wvr = (const float*)d_in[9];
    const float* wvi = (const float*)d_in[10];

    float* out = (float*)d_out;
    float* o_zr  = out;
    float* o_zi  = out + 16384 * 64;
    float* o_mem = out + 2 * 16384 * 64;
    float* o_np  = o_mem + 16384 * 16 * 128;
    float* o_act = o_np + 16384 * 16;

    int*   cnt = (int*)d_ws;
    float* G   = (float*)((char*)d_ws + 256);
    float* Mv  = G + 128 * 128;
    unsigned short* Gfr  = (unsigned short*)(Mv + 128 * 128);
    unsigned short* Mvfr = Gfr + 32768;

    hipLaunchKernelGGL(prep_kernel, dim3(128), dim3(128), 0, stream,
                       wqr, wqi, wkr, wki, wvr, wvi, G, Mv, cnt);
    hipLaunchKernelGGL(prep_frag, dim3(64), dim3(64), 0, stream, G, Mv, Gfr, Mvfr);
    hipLaunchKernelGGL(crsn_main, dim3(GRID), dim3(BLK), 0, stream,
                       z_real, z_imag, mem, ptr, ctrl, Gfr, Mvfr,
                       o_zr, o_zi, o_mem, o_np, cnt);
    hipLaunchKernelGGL(fin_kernel, dim3(1), dim3(1), 0, stream, cnt, o_act);
}